// Round 2
// baseline (127.747 us; speedup 1.0000x reference)
//
#include <hip/hip_runtime.h>

// Chamfer loss: B=32, N=M=2048, D=3.
// loss[b] = 0.5 * ( sum_n ma[n]*min_m d2(a_n,b_m) + sum_m mb[m]*min_n d2(b_m,a_n) )
// masked pairs -> BIG^2 = 1e16 (exact in fp32: a2 < ulp(1e16)).
//
// R7: R6's direction fusion was right but spilled: WRITE_SIZE showed 139 MB
// of scratch (cacc[16] demoted to local memory; #pragma unroll not fully
// honored + unions). This version force-allocates the 16 column-min
// accumulators as NAMED v2f registers via macro expansion (compile-time
// indices everywhere), drops the unions, keeps the 1-deep LDS prefetch.
// Also adds an XCD-aware block remap (all 32 chunks of a batch b on one
// XCD) so the 57 KB/b staged slice hits per-XCD L2 once scratch thrash is
// gone. Deterministic, atomic-free, re-poison-safe.
#define B_    32
#define N_    2048
#define M_    2048
#define RW_   8        // rows per wave
#define CH_   32       // row chunks per b: 2048 / (8 waves * 8 rows)
#define BIG2  1.0e16f
#define FINF  3.4e38f

typedef float v2f __attribute__((ext_vector_type(2)));

__device__ __forceinline__ v2f v2_fma(v2f a, v2f b, v2f c) {
#if __has_builtin(__builtin_elementwise_fma)
    return __builtin_elementwise_fma(a, b, c);
#else
    v2f r; r.x = fmaf(a.x, b.x, c.x); r.y = fmaf(a.y, b.y, c.y); return r;
#endif
}
__device__ __forceinline__ v2f v2_min(v2f a, v2f b) {
#if __has_builtin(__builtin_elementwise_min)
    return __builtin_elementwise_min(a, b);
#else
    v2f r; r.x = fminf(a.x, b.x); r.y = fminf(a.y, b.y); return r;
#endif
}
__device__ __forceinline__ v2f v2_splat(float s) { return (v2f){ s, s }; }

// Fused main: grid (CH_, B_) remapped XCD-aware, 512 threads (8 waves).
// Wave wv owns rows [chunk*64 + wv*8, +8) of the OUTPUT side. TARGET side
// staged in LDS as point-PAIR SoA:
//   sqA[p] = {-2x_{2p}, -2x_{2p+1}, -2y_{2p}, -2y_{2p+1}}
//   sqB[p] = {-2z_{2p}, -2z_{2p+1},  w_{2p},   w_{2p+1}}  (w = mask?|p|^2:1e16)
// Tile = 64 lanes x 2 points; per tile per row: 1 pk_add (fold ca2) +
// 3 pk_fma + 2 pk_min (row acc + col acc).
__global__ __launch_bounds__(512) void chamfer_fused(
    const int* __restrict__ o_w, const float* __restrict__ o_pts,
    const int* __restrict__ t_w, const float* __restrict__ t_pts,
    float* __restrict__ rowpart,      // [B_][CH_]
    float* __restrict__ colpart)      // [B_][CH_][M_]
{
    // XCD-aware remap: hw linear id i = bx + 32*by round-robins over 8 XCDs
    // (xcd = i%8). Map so all 32 chunks of a given b share one XCD:
    //   b = (i%8)*4 + (i/8)%4, chunk = (i/8)/4. Bijective over 1024 blocks.
    const int ilin  = blockIdx.x + CH_ * blockIdx.y;
    const int b     = (ilin & 7) * 4 + ((ilin >> 3) & 3);
    const int chunk = ilin >> 5;
    const int tid   = threadIdx.x;
    const int lane  = tid & 63;
    const int wv    = tid >> 6;
    const int row0  = chunk * (8 * RW_) + wv * RW_;

    __shared__ float4 sq[2048];        // 32 KB: sqA = sq[0:1024), sqB = sq[1024:2048)
    __shared__ float  wsum[8];
    float4* sqA = sq;
    float4* sqB = sq + 1024;
    float*  colbuf = (float*)sq;       // reused as [4][2048] after the inner loop

    // ---- Stage target slice: 512 threads x 2 pair-slots, coalesced float2.
    {
        const float2* src2 = (const float2*)(t_pts + (size_t)b * M_ * 3);
        const int2*   wb2  = (const int2*)(t_w + (size_t)b * M_);
        #pragma unroll
        for (int k = 0; k < 2; ++k) {
            int p = tid + k * 512;                 // pair index 0..1023
            float2 u0 = src2[p * 3 + 0];
            float2 u1 = src2[p * 3 + 1];
            float2 u2 = src2[p * 3 + 2];
            int2   mm = wb2[p];
            float x0 = u0.x, y0 = u0.y, z0 = u1.x;
            float x1 = u1.y, y1 = u2.x, z1 = u2.y;
            float n20 = fmaf(x0, x0, fmaf(y0, y0, z0 * z0));
            float n21 = fmaf(x1, x1, fmaf(y1, y1, z1 * z1));
            sqA[p] = make_float4(-2.f * x0, -2.f * x1, -2.f * y0, -2.f * y1);
            sqB[p] = make_float4(-2.f * z0, -2.f * z1,
                                 mm.x ? n20 : BIG2, mm.y ? n21 : BIG2);
        }
    }

    // ---- Row constants (wave-uniform base -> s_loads where possible).
    int base  = __builtin_amdgcn_readfirstlane((b * N_ + row0) * 3);
    int mbase = __builtin_amdgcn_readfirstlane(b * N_ + row0);
    const float* rp = o_pts + base;
    const int*   wp = o_w + mbase;
    float rx[RW_], ry[RW_], rz[RW_], ca2[RW_];
    int   msk[RW_];
    #pragma unroll
    for (int r = 0; r < RW_; ++r) {
        rx[r] = rp[3 * r + 0];
        ry[r] = rp[3 * r + 1];
        rz[r] = rp[3 * r + 2];
        msk[r] = wp[r];
        float a2 = fmaf(rx[r], rx[r], fmaf(ry[r], ry[r], rz[r] * rz[r]));
        ca2[r] = msk[r] ? a2 : BIG2;   // masked row contributes BIG2 to col-mins
    }
    __syncthreads();

    v2f racc[RW_];
    #pragma unroll
    for (int r = 0; r < RW_; ++r) racc[r] = v2_splat(FINF);

    // 16 NAMED column-min accumulators -> guaranteed VGPRs (no runtime index).
    v2f c0  = v2_splat(FINF), c1  = v2_splat(FINF), c2  = v2_splat(FINF), c3  = v2_splat(FINF);
    v2f c4  = v2_splat(FINF), c5  = v2_splat(FINF), c6  = v2_splat(FINF), c7  = v2_splat(FINF);
    v2f c8  = v2_splat(FINF), c9  = v2_splat(FINF), c10 = v2_splat(FINF), c11 = v2_splat(FINF);
    v2f c12 = v2_splat(FINF), c13 = v2_splat(FINF), c14 = v2_splat(FINF), c15 = v2_splat(FINF);

    // ---- Inner loop: 16 tiles of 128 points, 1-deep prefetch, macro-unrolled.
    float4 A  = sqA[lane];
    float4 Bq = sqB[lane];
    float4 An, Bn;

#define TILE(T, CT)                                                        \
    {                                                                      \
        if ((T) + 1 < 16) {                                                \
            An = sqA[((T) + 1) * 64 + lane];                               \
            Bn = sqB[((T) + 1) * 64 + lane];                               \
        }                                                                  \
        v2f xs = (v2f){ A.x,  A.y  };                                      \
        v2f ys = (v2f){ A.z,  A.w  };                                      \
        v2f zs = (v2f){ Bq.x, Bq.y };                                      \
        v2f ws = (v2f){ Bq.z, Bq.w };                                      \
        _Pragma("unroll")                                                  \
        for (int r = 0; r < RW_; ++r) {                                    \
            v2f wr = ws + v2_splat(ca2[r]);                                \
            v2f d  = v2_fma(v2_splat(rx[r]), xs,                           \
                     v2_fma(v2_splat(ry[r]), ys,                           \
                     v2_fma(v2_splat(rz[r]), zs, wr)));                    \
            racc[r] = v2_min(racc[r], d);                                  \
            CT      = v2_min(CT, d);                                       \
        }                                                                  \
        if ((T) + 1 < 16) { A = An; Bq = Bn; }                             \
    }

    TILE(0,  c0)  TILE(1,  c1)  TILE(2,  c2)  TILE(3,  c3)
    TILE(4,  c4)  TILE(5,  c5)  TILE(6,  c6)  TILE(7,  c7)
    TILE(8,  c8)  TILE(9,  c9)  TILE(10, c10) TILE(11, c11)
    TILE(12, c12) TILE(13, c13) TILE(14, c14) TILE(15, c15)
#undef TILE

    // ---- Row side: cross-lane min per row + masked sum (registers only).
    // racc already includes a2 (monotone-safe fold; proven path).
    float sum = 0.0f;
    #pragma unroll
    for (int r = 0; r < RW_; ++r) {
        float m = fminf(racc[r].x, racc[r].y);
        #pragma unroll
        for (int off = 32; off; off >>= 1)
            m = fminf(m, __shfl_xor(m, off, 64));
        sum += msk[r] ? fmaxf(m, 0.0f) : 0.0f;
    }
    if (lane == 0) wsum[wv] = sum;

    __syncthreads();   // all waves done reading sq; wsum visible

#define FOR_ALL_C(F)                                                       \
    F(0,  c0)  F(1,  c1)  F(2,  c2)  F(3,  c3)                             \
    F(4,  c4)  F(5,  c5)  F(6,  c6)  F(7,  c7)                             \
    F(8,  c8)  F(9,  c9)  F(10, c10) F(11, c11)                            \
    F(12, c12) F(13, c13) F(14, c14) F(15, c15)

    // ---- Col side: 8-wave tree min reusing the stage LDS as colbuf[4][2048].
    // Round A: waves 4..7 deposit their accumulators.
    if (wv >= 4) {
#define PUTC(T, CT) *(v2f*)&colbuf[(wv - 4) * 2048 + (T) * 128 + 2 * lane] = CT;
        FOR_ALL_C(PUTC)
#undef PUTC
    }
    __syncthreads();
    // Round B: waves 0..3 fold theirs in. tid 0 emits the row partial.
    if (wv < 4) {
#define FOLDC(T, CT)                                                       \
        {                                                                  \
            v2f* p = (v2f*)&colbuf[wv * 2048 + (T) * 128 + 2 * lane];      \
            *p = v2_min(*p, CT);                                           \
        }
        FOR_ALL_C(FOLDC)
#undef FOLDC
    }
    if (tid == 0) {
        float s = 0.f;
        #pragma unroll
        for (int i = 0; i < 8; ++i) s += wsum[i];
        rowpart[b * CH_ + chunk] = s;
    }
    __syncthreads();
    // Round C: 4 arrays -> 2.
    if (wv < 2) {
        #pragma unroll
        for (int t = 0; t < 16; ++t) {
            int c = t * 128 + 2 * lane;
            v2f a  = *(v2f*)&colbuf[wv * 2048 + c];
            v2f bb = *(v2f*)&colbuf[(wv + 2) * 2048 + c];
            *(v2f*)&colbuf[wv * 2048 + c] = v2_min(a, bb);
        }
    }
    __syncthreads();
    // Round D: 2 -> 1 and coalesced float4 store of the block's col partials.
    {
        float4 a  = *(float4*)&colbuf[0 * 2048 + tid * 4];
        float4 bb = *(float4*)&colbuf[1 * 2048 + tid * 4];
        float4 mn;
        mn.x = fminf(a.x, bb.x);
        mn.y = fminf(a.y, bb.y);
        mn.z = fminf(a.z, bb.z);
        mn.w = fminf(a.w, bb.w);
        *(float4*)&colpart[((size_t)b * CH_ + chunk) * M_ + tid * 4] = mn;
    }
#undef FOR_ALL_C
}

// Finish: 32 blocks (one per b), 512 threads. Thread t owns 4 cols: min over
// the 32 chunk partials (coalesced float4, stride 8 KB), mask+clamp+sum, add
// the 32 row partials, block-reduce, one store.
__global__ __launch_bounds__(512) void chamfer_finish2(
    const float* __restrict__ rowpart, const float* __restrict__ colpart,
    const int* __restrict__ t_w, float* __restrict__ loss)
{
    const int b = blockIdx.x, tid = threadIdx.x;
    const int lane = tid & 63, wv = tid >> 6;
    const float4* cp = (const float4*)(colpart + (size_t)b * CH_ * M_);
    float4 mn = cp[tid];
    #pragma unroll 8
    for (int k = 1; k < CH_; ++k) {
        float4 v = cp[k * 512 + tid];
        mn.x = fminf(mn.x, v.x);
        mn.y = fminf(mn.y, v.y);
        mn.z = fminf(mn.z, v.z);
        mn.w = fminf(mn.w, v.w);
    }
    int4 mm = ((const int4*)(t_w + (size_t)b * M_))[tid];
    float s = (mm.x ? fmaxf(mn.x, 0.f) : 0.f)
            + (mm.y ? fmaxf(mn.y, 0.f) : 0.f)
            + (mm.z ? fmaxf(mn.z, 0.f) : 0.f)
            + (mm.w ? fmaxf(mn.w, 0.f) : 0.f);
    if (tid < CH_) s += rowpart[b * CH_ + tid];
    #pragma unroll
    for (int off = 32; off; off >>= 1) s += __shfl_xor(s, off, 64);
    __shared__ float ws8[8];
    if (lane == 0) ws8[wv] = s;
    __syncthreads();
    if (tid == 0) {
        float tot = 0.f;
        #pragma unroll
        for (int i = 0; i < 8; ++i) tot += ws8[i];
        loss[b] = 0.5f * tot;
    }
}

// ---------- Fallback (ws too small): prep-on-the-fly + atomics ----------
__global__ void chamfer_zero(float* __restrict__ loss)
{
    if (threadIdx.x < B_) loss[threadIdx.x] = 0.0f;
}

__global__ __launch_bounds__(256) void chamfer_nolds(
    const int* __restrict__ o_w, const float* __restrict__ o_pts,
    const int* __restrict__ t_w, const float* __restrict__ t_pts,
    float* __restrict__ loss)
{
    const int dir  = blockIdx.z;
    const int b    = blockIdx.y;
    const int lane = threadIdx.x & 63;
    const int wv   = threadIdx.x >> 6;
    const int row0 = (blockIdx.x * 4 + wv) * 16;

    const int*   __restrict__ wa = (dir == 0) ? o_w   : t_w;
    const float* __restrict__ pa = (dir == 0) ? o_pts : t_pts;
    const int*   __restrict__ wb = (dir == 0) ? t_w   : o_w;
    const float* __restrict__ pb = (dir == 0) ? t_pts : o_pts;

    int base = __builtin_amdgcn_readfirstlane((b * N_ + row0) * 3);
    const float* rp = pa + base;
    float rx[16], ry[16], rz[16];
    #pragma unroll
    for (int r = 0; r < 16; ++r) {
        rx[r] = rp[3 * r + 0];
        ry[r] = rp[3 * r + 1];
        rz[r] = rp[3 * r + 2];
    }
    float acc[16];
    #pragma unroll
    for (int r = 0; r < 16; ++r) acc[r] = 3.4e38f;

    #pragma unroll 2
    for (int t = 0; t < M_ / 64; ++t) {
        int ib = b * M_ + t * 64 + lane;
        float bx = pb[ib * 3 + 0], by = pb[ib * 3 + 1], bz = pb[ib * 3 + 2];
        float n2 = fmaf(bx, bx, fmaf(by, by, bz * bz));
        float qw = (wb[ib] != 0) ? n2 : BIG2;
        float qx = -2.0f * bx, qy = -2.0f * by, qz = -2.0f * bz;
        #pragma unroll
        for (int r = 0; r < 16; ++r) {
            float d = fmaf(rx[r], qx, fmaf(ry[r], qy, fmaf(rz[r], qz, qw)));
            acc[r] = fminf(acc[r], d);
        }
    }
    #pragma unroll
    for (int r = 0; r < 16; ++r) {
        float v = acc[r];
        #pragma unroll
        for (int off = 32; off; off >>= 1) v = fminf(v, __shfl_xor(v, off, 64));
        acc[r] = v;
    }
    int mbase = __builtin_amdgcn_readfirstlane(b * N_ + row0);
    const int* wp = wa + mbase;
    float sum = 0.0f;
    #pragma unroll
    for (int r = 0; r < 16; ++r) {
        float a2 = fmaf(rx[r], rx[r], fmaf(ry[r], ry[r], rz[r] * rz[r]));
        float d2 = fmaxf(a2 + acc[r], 0.0f);
        sum += (wp[r] != 0) ? d2 : 0.0f;
    }
    if (lane == 0) atomicAdd(&loss[b], 0.5f * sum);
}

extern "C" void kernel_launch(void* const* d_in, const int* in_sizes, int n_in,
                              void* d_out, int out_size, void* d_ws, size_t ws_size,
                              hipStream_t stream) {
    const int*   o_w   = (const int*)  d_in[0];
    const float* o_pts = (const float*)d_in[1];
    const int*   t_w   = (const int*)  d_in[2];
    const float* t_pts = (const float*)d_in[3];
    float* loss = (float*)d_out;

    const size_t row_bytes = (size_t)B_ * CH_ * sizeof(float);        // 4 KB
    const size_t col_bytes = (size_t)B_ * CH_ * M_ * sizeof(float);   // 8 MB

    if (ws_size >= row_bytes + col_bytes) {
        float* rowpart = (float*)d_ws;                 // [B][CH]
        float* colpart = (float*)d_ws + B_ * CH_;      // [B][CH][M], 16B-aligned
        dim3 grid(CH_, B_);                            // (32, 32) -> remapped in-kernel
        chamfer_fused<<<grid, 512, 0, stream>>>(
            o_w, o_pts, t_w, t_pts, rowpart, colpart);
        chamfer_finish2<<<B_, 512, 0, stream>>>(rowpart, colpart, t_w, loss);
    } else {
        chamfer_zero<<<1, 64, 0, stream>>>(loss);
        dim3 grid(N_ / 64, B_, 2);
        chamfer_nolds<<<grid, 256, 0, stream>>>(
            o_w, o_pts, t_w, t_pts, loss);
    }
}

// Round 3
// 87.166 us; speedup vs baseline: 1.4656x; 1.4656x over previous
//
#include <hip/hip_runtime.h>

// Chamfer loss: B=32, N=M=2048, D=3.
// loss[b] = 0.5 * ( sum_n ma[n]*min_m d2(a_n,b_m) + sum_m mb[m]*min_n d2(b_m,a_n) )
// masked pairs -> BIG^2 = 1e16 (exact in fp32: a2 < ulp(1e16)).
//
// R8: revert to the PROVEN R5 two-pass structure (85.65us, absmax 0.0) --
// the R6/R7 direction-fusion carried 150 MB of unexplained HBM writes that
// two independent register-allocation rewrites did not change. One scaling
// change vs R5: RW_=16 rows/wave (128 rows/block), grid (16,32,2)=1024
// blocks = exactly whole-grid-resident (256 CU x 4 blocks, LDS-capped).
// Halves staging volume and barrier/epilogue count per row; VALU floor
// unchanged (6.8us). Also serves as a bisect: chamfer_main's own
// FETCH/WRITE counters will finally be visible in top-5.
#define B_    32
#define N_    2048
#define M_    2048
#define RW_   16       // rows per wave
#define GX_   16       // n-chunks per (b,dir): 2048 / (8 waves * 16 rows)
#define BIG2  1.0e16f

typedef float v2f __attribute__((ext_vector_type(2)));

__device__ __forceinline__ v2f v2_fma(v2f a, v2f b, v2f c) {
#if __has_builtin(__builtin_elementwise_fma)
    return __builtin_elementwise_fma(a, b, c);
#else
    v2f r; r.x = fmaf(a.x, b.x, c.x); r.y = fmaf(a.y, b.y, c.y); return r;
#endif
}
__device__ __forceinline__ v2f v2_min(v2f a, v2f b) {
#if __has_builtin(__builtin_elementwise_min)
    return __builtin_elementwise_min(a, b);
#else
    v2f r; r.x = fminf(a.x, b.x); r.y = fminf(a.y, b.y); return r;
#endif
}
__device__ __forceinline__ v2f v2_splat(float s) { return (v2f){ s, s }; }

union F4V2 { float4 f4; struct { v2f lo, hi; } v; };

// Main: grid (GX_, B_, 2), 512 threads (8 waves). Wave wv owns rows
// [bx*128 + wv*16, +16) in SGPRs/VGPRs. Inner side staged in LDS as
// point-PAIR SoA (R5 layout, proven):
//   sqA[p] = {-2x_{2p}, -2x_{2p+1}, -2y_{2p}, -2y_{2p+1}}
//   sqB[p] = {-2z_{2p}, -2z_{2p+1},  w_{2p},   w_{2p+1}}   (w = mask?|p|^2:1e16)
// Tile = 64 lanes x 2 points = 128 points; per tile: 2 ds_read_b128 +
// (3 pk_fma + 1 pk_min) x 16 rows.
__global__ __launch_bounds__(512) void chamfer_main(
    const int* __restrict__ o_w, const float* __restrict__ o_pts,
    const int* __restrict__ t_w, const float* __restrict__ t_pts,
    float* __restrict__ partials)
{
    const int dir  = blockIdx.z;
    const int b    = blockIdx.y;
    const int tid  = threadIdx.x;
    const int lane = tid & 63;
    const int wv   = tid >> 6;
    const int row0 = blockIdx.x * (8 * RW_) + wv * RW_;

    const int*   wa; const float* pa;   // outer (row) side
    const int*   wb; const float* pb;   // inner (streamed) side
    if (dir == 0) { wa = o_w; pa = o_pts; wb = t_w; pb = t_pts; }
    else          { wa = t_w; pa = t_pts; wb = o_w; pb = o_pts; }

    __shared__ float4 sqA[M_ / 2];      // 16 KB
    __shared__ float4 sqB[M_ / 2];      // 16 KB
    __shared__ float  wsum[8];

    // ---- Stage inner slice: 512 threads x 2 pair-slots, coalesced float2.
    {
        const float2* src2 = (const float2*)(pb + (size_t)b * M_ * 3);
        const int2*   wb2  = (const int2*)(wb + (size_t)b * M_);
        #pragma unroll
        for (int k = 0; k < 2; ++k) {
            int p = tid + k * 512;                     // pair index 0..1023
            float2 u0 = src2[p * 3 + 0];
            float2 u1 = src2[p * 3 + 1];
            float2 u2 = src2[p * 3 + 2];
            int2   mm = wb2[p];
            float x0 = u0.x, y0 = u0.y, z0 = u1.x;
            float x1 = u1.y, y1 = u2.x, z1 = u2.y;
            float n20 = fmaf(x0, x0, fmaf(y0, y0, z0 * z0));
            float n21 = fmaf(x1, x1, fmaf(y1, y1, z1 * z1));
            sqA[p] = make_float4(-2.f * x0, -2.f * x1, -2.f * y0, -2.f * y1);
            sqB[p] = make_float4(-2.f * z0, -2.f * z1,
                                 mm.x ? n20 : BIG2, mm.y ? n21 : BIG2);
        }
    }

    // ---- Row constants (wave-uniform base -> scalar loads where possible).
    int base = __builtin_amdgcn_readfirstlane((b * N_ + row0) * 3);
    const float* rp = pa + base;
    float rx[RW_], ry[RW_], rz[RW_];
    #pragma unroll
    for (int r = 0; r < RW_; ++r) {
        rx[r] = rp[3 * r + 0];
        ry[r] = rp[3 * r + 1];
        rz[r] = rp[3 * r + 2];
    }
    __syncthreads();

    v2f acc[RW_];
    #pragma unroll
    for (int r = 0; r < RW_; ++r) acc[r] = v2_splat(3.4e38f);

    // ---- Inner loop: 16 tiles of 128 points, 1-deep LDS prefetch.
    F4V2 qa, qb, na, nb;
    qa.f4 = sqA[lane];
    qb.f4 = sqB[lane];
    #pragma unroll 4
    for (int t = 0; t < M_ / 128; ++t) {
        if (t + 1 < M_ / 128) {
            na.f4 = sqA[(t + 1) * 64 + lane];
            nb.f4 = sqB[(t + 1) * 64 + lane];
        }
        v2f xs = qa.v.lo, ys = qa.v.hi, zs = qb.v.lo, ws = qb.v.hi;
        #pragma unroll
        for (int r = 0; r < RW_; ++r) {
            v2f d = v2_fma(v2_splat(rx[r]), xs,
                    v2_fma(v2_splat(ry[r]), ys,
                    v2_fma(v2_splat(rz[r]), zs, ws)));
            acc[r] = v2_min(acc[r], d);
        }
        qa = na; qb = nb;
    }

    // ---- Cross-lane min per row, epilogue, block reduce, one store.
    int mbase = __builtin_amdgcn_readfirstlane(b * N_ + row0);
    const int* wp = wa + mbase;
    float sum = 0.0f;
    #pragma unroll
    for (int r = 0; r < RW_; ++r) {
        float m = fminf(acc[r].x, acc[r].y);
        #pragma unroll
        for (int off = 32; off; off >>= 1)
            m = fminf(m, __shfl_xor(m, off, 64));
        float a2 = fmaf(rx[r], rx[r], fmaf(ry[r], ry[r], rz[r] * rz[r]));
        float d2 = fmaxf(a2 + m, 0.0f);
        sum += (wp[r] != 0) ? d2 : 0.0f;
    }
    if (lane == 0) wsum[wv] = sum;
    __syncthreads();
    if (tid == 0) {
        float s = 0.f;
        #pragma unroll
        for (int i = 0; i < 8; ++i) s += wsum[i];
        partials[((size_t)b * 2 + dir) * GX_ + blockIdx.x] = s;
    }
}

// Finish: one block, 256 threads. Thread t: b = t>>3, k = t&7 reads one
// float4 of the 32 partials for batch b (2*GX_=32 floats = 8 float4),
// then 3-step shfl reduce within the 8-lane group.
__global__ __launch_bounds__(256) void chamfer_finish(
    const float* __restrict__ partials, float* __restrict__ loss)
{
    int t = threadIdx.x;
    int b = t >> 3, k = t & 7;
    const float4* p4 = (const float4*)(partials + b * (2 * GX_));
    float4 u = p4[k];
    float s = (u.x + u.y) + (u.z + u.w);
    #pragma unroll
    for (int off = 4; off; off >>= 1) s += __shfl_xor(s, off, 64);
    if (k == 0) loss[b] = 0.5f * s;
}

// ---------- Fallback (ws too small): prep-on-the-fly + atomics ----------
__global__ void chamfer_zero(float* __restrict__ loss)
{
    if (threadIdx.x < B_) loss[threadIdx.x] = 0.0f;
}

__global__ __launch_bounds__(256) void chamfer_nolds(
    const int* __restrict__ o_w, const float* __restrict__ o_pts,
    const int* __restrict__ t_w, const float* __restrict__ t_pts,
    float* __restrict__ loss)
{
    const int dir  = blockIdx.z;
    const int b    = blockIdx.y;
    const int lane = threadIdx.x & 63;
    const int wv   = threadIdx.x >> 6;
    const int row0 = (blockIdx.x * 4 + wv) * 16;

    const int*   __restrict__ wa = (dir == 0) ? o_w   : t_w;
    const float* __restrict__ pa = (dir == 0) ? o_pts : t_pts;
    const int*   __restrict__ wb = (dir == 0) ? t_w   : o_w;
    const float* __restrict__ pb = (dir == 0) ? t_pts : o_pts;

    int base = __builtin_amdgcn_readfirstlane((b * N_ + row0) * 3);
    const float* rp = pa + base;
    float rx[16], ry[16], rz[16];
    #pragma unroll
    for (int r = 0; r < 16; ++r) {
        rx[r] = rp[3 * r + 0];
        ry[r] = rp[3 * r + 1];
        rz[r] = rp[3 * r + 2];
    }
    float acc[16];
    #pragma unroll
    for (int r = 0; r < 16; ++r) acc[r] = 3.4e38f;

    #pragma unroll 2
    for (int t = 0; t < M_ / 64; ++t) {
        int ib = b * M_ + t * 64 + lane;
        float bx = pb[ib * 3 + 0], by = pb[ib * 3 + 1], bz = pb[ib * 3 + 2];
        float n2 = fmaf(bx, bx, fmaf(by, by, bz * bz));
        float qw = (wb[ib] != 0) ? n2 : BIG2;
        float qx = -2.0f * bx, qy = -2.0f * by, qz = -2.0f * bz;
        #pragma unroll
        for (int r = 0; r < 16; ++r) {
            float d = fmaf(rx[r], qx, fmaf(ry[r], qy, fmaf(rz[r], qz, qw)));
            acc[r] = fminf(acc[r], d);
        }
    }
    #pragma unroll
    for (int r = 0; r < 16; ++r) {
        float v = acc[r];
        #pragma unroll
        for (int off = 32; off; off >>= 1) v = fminf(v, __shfl_xor(v, off, 64));
        acc[r] = v;
    }
    int mbase = __builtin_amdgcn_readfirstlane(b * N_ + row0);
    const int* wp = wa + mbase;
    float sum = 0.0f;
    #pragma unroll
    for (int r = 0; r < 16; ++r) {
        float a2 = fmaf(rx[r], rx[r], fmaf(ry[r], ry[r], rz[r] * rz[r]));
        float d2 = fmaxf(a2 + acc[r], 0.0f);
        sum += (wp[r] != 0) ? d2 : 0.0f;
    }
    if (lane == 0) atomicAdd(&loss[b], 0.5f * sum);
}

extern "C" void kernel_launch(void* const* d_in, const int* in_sizes, int n_in,
                              void* d_out, int out_size, void* d_ws, size_t ws_size,
                              hipStream_t stream) {
    const int*   o_w   = (const int*)  d_in[0];
    const float* o_pts = (const float*)d_in[1];
    const int*   t_w   = (const int*)  d_in[2];
    const float* t_pts = (const float*)d_in[3];
    float* loss = (float*)d_out;

    const size_t part_bytes = (size_t)B_ * 2 * GX_ * sizeof(float);   // 4 KB

    if (ws_size >= part_bytes) {
        float* partials = (float*)d_ws;
        dim3 grid(GX_, B_, 2);                                        // (16, 32, 2)
        chamfer_main<<<grid, 512, 0, stream>>>(
            o_w, o_pts, t_w, t_pts, partials);
        chamfer_finish<<<1, 256, 0, stream>>>(partials, loss);
    } else {
        chamfer_zero<<<1, 64, 0, stream>>>(loss);
        dim3 grid(N_ / 64, B_, 2);
        chamfer_nolds<<<grid, 256, 0, stream>>>(
            o_w, o_pts, t_w, t_pts, loss);
    }
}